// Round 1
// baseline (58.981 us; speedup 1.0000x reference)
//
#include <hip/hip_runtime.h>

// EMA along last dim:  y[b,c,0] = x[b,c,0];  y[b,c,i] = (1-a_c)*y[b,c,i-1] + a_c*x[b,c,i]
// x: [B, C, L] f32 row-major (L contiguous), alpha: [1, C] f32, out: [B, C, L] f32.
//
// One wave (64 lanes) per row. Row length L = 2048 = 64 lanes * 32 elems/lane.
// Per-lane chunk scan with zero init -> affine-map Kogge-Stone wave scan -> correction.

#define CHUNK 32           // elements per lane (must be multiple of 4)
#define ROW_LEN 2048       // L = 64 * CHUNK
#define WAVES_PER_BLOCK 4  // 256 threads/block

__global__ __launch_bounds__(256)
void ema_rows_kernel(const float* __restrict__ x,
                     const float* __restrict__ alpha,
                     float* __restrict__ out,
                     int C, int nrows) {
    const int wave_in_block = threadIdx.x >> 6;
    const int lane = threadIdx.x & 63;
    const int row = blockIdx.x * WAVES_PER_BLOCK + wave_in_block;
    if (row >= nrows) return;

    const int c = row % C;               // row = b*C + c
    const float a = alpha[c];            // wave-uniform (scalar-cached)
    const float cm = 1.0f - a;

    const float* __restrict__ xrow = x + (size_t)row * ROW_LEN;
    float* __restrict__ orow = out + (size_t)row * ROW_LEN;

    // ---- load this lane's 32 contiguous elements (8 x float4) ----
    float p[CHUNK];
    const float4* __restrict__ xv =
        reinterpret_cast<const float4*>(xrow + lane * CHUNK);
    #pragma unroll
    for (int j = 0; j < CHUNK / 4; ++j) {
        float4 v = xv[j];
        p[4 * j + 0] = v.x;
        p[4 * j + 1] = v.y;
        p[4 * j + 2] = v.z;
        p[4 * j + 3] = v.w;
    }

    // ---- provisional chunk scan, zero initial state ----
    // Lane 0 is the true row head: y_0 = x_0 (map has A-coeff 0).
    // Other lanes: first element follows the normal recurrence from state 0.
    p[0] = (lane == 0) ? p[0] : a * p[0];
    #pragma unroll
    for (int j = 1; j < CHUNK; ++j) {
        p[j] = fmaf(cm, p[j - 1], a * p[j]);
    }

    // ---- compose per-chunk affine maps across the wave ----
    // Chunk map: y_out = A * y_in + B, with A = cm^32 (lane 0: A = 0), B = p[31].
    float A = cm * cm;       // cm^2
    A = A * A;               // ^4
    A = A * A;               // ^8
    A = A * A;               // ^16
    A = A * A;               // ^32
    if (lane == 0) A = 0.0f;
    float Bv = p[CHUNK - 1];

    #pragma unroll
    for (int off = 1; off < 64; off <<= 1) {
        float Ap = __shfl_up(A, off, 64);
        float Bp = __shfl_up(Bv, off, 64);
        if (lane >= off) {
            Bv = fmaf(A, Bp, Bv);   // compose: this-map ∘ prev-map
            A = A * Ap;
        }
    }

    // Exclusive carry: state entering this lane's chunk.
    float s = __shfl_up(Bv, 1, 64);
    float t = (lane == 0) ? 0.0f : s;

    // ---- correction: y_j = p_j + cm^{j+1} * s ----
    #pragma unroll
    for (int j = 0; j < CHUNK; ++j) {
        t *= cm;
        p[j] += t;
    }

    // ---- store (8 x float4) ----
    float4* __restrict__ ov = reinterpret_cast<float4*>(orow + lane * CHUNK);
    #pragma unroll
    for (int j = 0; j < CHUNK / 4; ++j) {
        float4 v;
        v.x = p[4 * j + 0];
        v.y = p[4 * j + 1];
        v.z = p[4 * j + 2];
        v.w = p[4 * j + 3];
        ov[j] = v;
    }
}

extern "C" void kernel_launch(void* const* d_in, const int* in_sizes, int n_in,
                              void* d_out, int out_size, void* d_ws, size_t ws_size,
                              hipStream_t stream) {
    const float* x = (const float*)d_in[0];
    const float* alpha = (const float*)d_in[1];
    float* out = (float*)d_out;

    const int C = in_sizes[1];                  // alpha is (1, C)
    const int nrows = in_sizes[0] / ROW_LEN;    // B * C

    const int blocks = (nrows + WAVES_PER_BLOCK - 1) / WAVES_PER_BLOCK;
    ema_rows_kernel<<<blocks, 64 * WAVES_PER_BLOCK, 0, stream>>>(x, alpha, out, C, nrows);
}

// Round 2
// 44.339 us; speedup vs baseline: 1.3302x; 1.3302x over previous
//
#include <hip/hip_runtime.h>

// EMA along last dim:  y[b,c,0] = x[b,c,0];  y[b,c,i] = (1-a_c)*y[b,c,i-1] + a_c*x[b,c,i]
// x: [B, C, L] f32 row-major (L contiguous), alpha: [1, C] f32, out: [B, C, L] f32.
//
// One wave per row; the row is processed in NROUND=8 rounds of 256 elements.
// Round j, lane l owns the 4 contiguous floats at (j*64 + l)*4 -> every global
// load/store instruction is a fully-coalesced 1 KiB access (vs the previous
// version's 128 B-strided 16 B accesses = 64 cache lines/instr).
//
// Per round: 4-elem serial scan from zero state -> affine (A=cm^4, B=p3) map
// Kogge-Stone scan across the wave -> per-lane incoming state -> correction.
// A scalar carry (state after element 256*(j+1)-1) chains the rounds.

#define ROW_LEN 2048
#define NROUND 8           // 8 rounds * 64 lanes * 4 floats = 2048
#define WAVES_PER_BLOCK 4  // 256 threads/block

__global__ __launch_bounds__(256)
void ema_rows_kernel(const float* __restrict__ x,
                     const float* __restrict__ alpha,
                     float* __restrict__ out,
                     int C, int nrows) {
    const int wave = threadIdx.x >> 6;
    const int lane = threadIdx.x & 63;
    const int row = blockIdx.x * WAVES_PER_BLOCK + wave;
    if (row >= nrows) return;

    const float a = alpha[row % C];     // wave-uniform
    const float cm = 1.0f - a;
    const float cm2 = cm * cm;
    const float cm3 = cm2 * cm;
    const float cm4 = cm2 * cm2;

    const float4* __restrict__ xv =
        reinterpret_cast<const float4*>(x + (size_t)row * ROW_LEN);
    float4* __restrict__ ov =
        reinterpret_cast<float4*>(out + (size_t)row * ROW_LEN);

    // Issue all 8 coalesced loads up front (independent -> max MLP).
    float4 v[NROUND];
    #pragma unroll
    for (int j = 0; j < NROUND; ++j) v[j] = xv[j * 64 + lane];

    float carry = 0.0f;  // row state entering round j (state after elem j*256-1)

    #pragma unroll
    for (int j = 0; j < NROUND; ++j) {
        // ---- provisional 4-elem scan from zero state ----
        float p0 = a * v[j].x;
        if (j == 0 && lane == 0) p0 = v[j].x;   // y_0 = x_0 (row head)
        float p1 = fmaf(cm, p0, a * v[j].y);
        float p2 = fmaf(cm, p1, a * v[j].z);
        float p3 = fmaf(cm, p2, a * v[j].w);

        // ---- affine map for this lane's chunk: y_out = A*y_in + B ----
        float A = (j == 0 && lane == 0) ? 0.0f : cm4;  // head kills history
        float Bv = p3;

        // Kogge-Stone inclusive scan of map composition across the wave.
        #pragma unroll
        for (int off = 1; off < 64; off <<= 1) {
            float Ap = __shfl_up(A, off, 64);
            float Bp = __shfl_up(Bv, off, 64);
            if (lane >= off) {
                Bv = fmaf(A, Bp, Bv);   // this ∘ prev
                A = A * Ap;
            }
        }

        // State after this lane's chunk, given round-incoming state `carry`.
        float S = fmaf(A, carry, Bv);
        // State entering this lane's chunk.
        float Sin = __shfl_up(S, 1, 64);
        if (lane == 0) Sin = carry;

        // ---- correction: y_k = p_k + cm^{k+1} * Sin  (independent FMAs) ----
        float4 y;
        y.x = fmaf(cm,  Sin, p0);
        y.y = fmaf(cm2, Sin, p1);
        y.z = fmaf(cm3, Sin, p2);
        y.w = fmaf(cm4, Sin, p3);

        ov[j * 64 + lane] = y;          // coalesced 1 KiB store

        carry = __shfl(S, 63, 64);      // chain to next round
    }
}

extern "C" void kernel_launch(void* const* d_in, const int* in_sizes, int n_in,
                              void* d_out, int out_size, void* d_ws, size_t ws_size,
                              hipStream_t stream) {
    const float* x = (const float*)d_in[0];
    const float* alpha = (const float*)d_in[1];
    float* out = (float*)d_out;

    const int C = in_sizes[1];                  // alpha is (1, C)
    const int nrows = in_sizes[0] / ROW_LEN;    // B * C

    const int blocks = (nrows + WAVES_PER_BLOCK - 1) / WAVES_PER_BLOCK;
    ema_rows_kernel<<<blocks, 64 * WAVES_PER_BLOCK, 0, stream>>>(x, alpha, out, C, nrows);
}

// Round 3
// 44.286 us; speedup vs baseline: 1.3318x; 1.0012x over previous
//
#include <hip/hip_runtime.h>

// EMA along last dim:  y[b,c,0] = x[b,c,0];  y[b,c,i] = (1-a_c)*y[b,c,i-1] + a_c*x[b,c,i]
// x: [B, C, L] f32 row-major, alpha: [1, C] f32, out: [B, C, L] f32.
//
// One wave per row, 8 rounds of 256 elements, fully-coalesced float4 accesses.
// Key restructure vs previous version: every lane-chunk's affine map has the
// KNOWN A-coefficient cm^4 (round 0's head zeroes the A-product entirely), so
//  - the Kogge-Stone scan only carries B, with wave-uniform multipliers
//    cm^{4*off}  -> 6 shuffles/round instead of 12, and
//  - all 8 rounds' scans are INDEPENDENT; the inter-round dependency is just
//    carry_{j+1} = cm^256 * carry_j + B63_j  (8 scalar FMAs).
// Output is stored non-temporally (nt) so the 128 MiB input stays L3-resident
// across graph replays and HBM traffic approaches write-only.

typedef float vfloat4 __attribute__((ext_vector_type(4)));

#define ROW_LEN 2048
#define NROUND 8           // 8 rounds * 64 lanes * 4 floats = 2048
#define WAVES_PER_BLOCK 4  // 256 threads/block

__global__ __launch_bounds__(256)
void ema_rows_kernel(const float* __restrict__ x,
                     const float* __restrict__ alpha,
                     float* __restrict__ out,
                     int C, int nrows) {
    const int wave = threadIdx.x >> 6;
    const int lane = threadIdx.x & 63;
    const int row = blockIdx.x * WAVES_PER_BLOCK + wave;
    if (row >= nrows) return;

    const float a  = alpha[row % C];       // wave-uniform
    const float cm = 1.0f - a;
    const float cm2 = cm * cm, cm3 = cm2 * cm, cm4 = cm2 * cm2;
    const float m1  = cm4;                 // cm^4
    const float m2  = m1 * m1;             // cm^8
    const float m4  = m2 * m2;             // cm^16
    const float m8  = m4 * m4;             // cm^32
    const float m16 = m8 * m8;             // cm^64
    const float m32 = m16 * m16;           // cm^128
    const float cm256 = m32 * m32;         // cm^256 (may underflow to 0 — fine)

    // cm^(4*lane) via lane-bit repeated squaring (exclusive-scan A coefficient)
    float cmp4l = 1.0f;
    if (lane & 1)  cmp4l *= m1;
    if (lane & 2)  cmp4l *= m2;
    if (lane & 4)  cmp4l *= m4;
    if (lane & 8)  cmp4l *= m8;
    if (lane & 16) cmp4l *= m16;
    if (lane & 32) cmp4l *= m32;

    const vfloat4* __restrict__ xv =
        reinterpret_cast<const vfloat4*>(x + (size_t)row * ROW_LEN);
    vfloat4* __restrict__ ov =
        reinterpret_cast<vfloat4*>(out + (size_t)row * ROW_LEN);

    // All 8 coalesced loads up front (independent -> max MLP).
    vfloat4 v[NROUND];
    #pragma unroll
    for (int j = 0; j < NROUND; ++j) v[j] = xv[j * 64 + lane];

    // Provisional 4-elem scans from zero state (all independent).
    float p[NROUND][4];
    float Bh[NROUND];
    #pragma unroll
    for (int j = 0; j < NROUND; ++j) {
        float p0 = a * v[j].x;
        if (j == 0 && lane == 0) p0 = v[j].x;   // y_0 = x_0 (row head)
        float p1 = fmaf(cm, p0, a * v[j].y);
        float p2 = fmaf(cm, p1, a * v[j].z);
        float p3 = fmaf(cm, p2, a * v[j].w);
        p[j][0] = p0; p[j][1] = p1; p[j][2] = p2; p[j][3] = p3;
        Bh[j] = p3;
    }

    // 6-step Kogge-Stone B-scan, 8 independent scans interleaved per step.
    #pragma unroll
    for (int s = 0; s < 6; ++s) {
        const int off = 1 << s;
        const float mult = (s == 0) ? m1 : (s == 1) ? m2 : (s == 2) ? m4
                         : (s == 3) ? m8 : (s == 4) ? m16 : m32;
        #pragma unroll
        for (int j = 0; j < NROUND; ++j) {
            float Bp = __shfl_up(Bh[j], off, 64);
            if (lane >= off) Bh[j] = fmaf(mult, Bp, Bh[j]);
        }
    }

    // Exclusive-scan value and lane-63 total per round (independent shuffles).
    float Bhp[NROUND], B63[NROUND];
    #pragma unroll
    for (int j = 0; j < NROUND; ++j) {
        float t = __shfl_up(Bh[j], 1, 64);
        Bhp[j] = (lane == 0) ? 0.0f : t;     // lane0: Sin = cmp4l(=1)*carry + 0
        B63[j] = __shfl(Bh[j], 63, 64);
    }

    // Correction + store; inter-round carry is an 8-FMA scalar chain.
    float carry = 0.0f;
    #pragma unroll
    for (int j = 0; j < NROUND; ++j) {
        const float Sin = fmaf(cmp4l, carry, Bhp[j]);   // state entering chunk
        vfloat4 y;
        y.x = fmaf(cm,  Sin, p[j][0]);
        y.y = fmaf(cm2, Sin, p[j][1]);
        y.z = fmaf(cm3, Sin, p[j][2]);
        y.w = fmaf(cm4, Sin, p[j][3]);
        __builtin_nontemporal_store(y, &ov[j * 64 + lane]);  // coalesced, no L3 alloc
        carry = fmaf(cm256, carry, B63[j]);
    }
}

extern "C" void kernel_launch(void* const* d_in, const int* in_sizes, int n_in,
                              void* d_out, int out_size, void* d_ws, size_t ws_size,
                              hipStream_t stream) {
    const float* x = (const float*)d_in[0];
    const float* alpha = (const float*)d_in[1];
    float* out = (float*)d_out;

    const int C = in_sizes[1];                  // alpha is (1, C)
    const int nrows = in_sizes[0] / ROW_LEN;    // B * C

    const int blocks = (nrows + WAVES_PER_BLOCK - 1) / WAVES_PER_BLOCK;
    ema_rows_kernel<<<blocks, 64 * WAVES_PER_BLOCK, 0, stream>>>(x, alpha, out, C, nrows);
}